// Round 2
// baseline (1001.345 us; speedup 1.0000x reference)
//
#include <hip/hip_runtime.h>
#include <hip/hip_bf16.h>
#include <stdint.h>

typedef unsigned int u32;
typedef unsigned short u16;

__device__ __forceinline__ float bf2f(u32 b) {
  union { u32 u; float f; } v; v.u = b << 16; return v.f;
}

// ---------- init: zero cnt + detect x dtype (bf16 vs fp32) ----------
// bf16 N(0,1): every u16, bf16-interpreted, has |v| < 2^13 (exp field < 140).
// fp32 N(0,1) reinterpreted as u16 pairs: low halves have ~uniform exponents,
// so ~half the u16s have exp >= 140. Threshold: >8 of 64 lanes saw one.
__global__ void FCAdaINLayer_68719477052_kernel(const u16* __restrict__ xb,
                                                int* __restrict__ cnt, int G,
                                                int* __restrict__ flag) {
  int t = blockIdx.x * blockDim.x + threadIdx.x;
  int stride = gridDim.x * blockDim.x;
  for (int i = t; i < G; i += stride) cnt[i] = 0;
  if (blockIdx.x == 0 && threadIdx.x < 64) {
    int lane = threadIdx.x;
    int big = 0;
    for (int j = lane; j < 2048; j += 64) {
      u32 e = ((u32)xb[j] >> 7) & 0xffu;
      if (e >= 140u) big++;
    }
    unsigned long long m = __ballot(big > 0);
    if (lane == 0) *flag = (__popcll(m) > 8) ? 1 : 0;
  }
}

// ---------- histogram ----------
__global__ void k_hist(const int* __restrict__ lat, int n, int* __restrict__ cnt) {
  int i = blockIdx.x * blockDim.x + threadIdx.x;
  int stride = gridDim.x * blockDim.x;
  for (; i < n; i += stride) atomicAdd(&cnt[lat[i]], 1);
}

// ---------- exclusive scan (1 block, 256 thr) ----------
__global__ void k_scan(const int* __restrict__ cnt, int G, int* __restrict__ offs,
                       int* __restrict__ cursor) {
  __shared__ int part[256];
  int t = threadIdx.x;
  int per = (G + 255) / 256;
  int base = t * per;
  int s = 0;
  for (int j = 0; j < per; j++) { int g = base + j; if (g < G) s += cnt[g]; }
  part[t] = s;
  __syncthreads();
  if (t == 0) {
    int run = 0;
    for (int j = 0; j < 256; j++) { int v = part[j]; part[j] = run; run += v; }
  }
  __syncthreads();
  int run = part[t];
  for (int j = 0; j < per; j++) {
    int g = base + j;
    if (g < G) { offs[g] = run; cursor[g] = run; run += cnt[g]; }
  }
  if (t == 255) offs[G] = run;
}

// ---------- scatter ----------
__global__ void k_scatter(const int* __restrict__ lat, int n, int* __restrict__ cursor,
                          int* __restrict__ sorted) {
  int i = blockIdx.x * blockDim.x + threadIdx.x;
  int stride = gridDim.x * blockDim.x;
  for (; i < n; i += stride) {
    int g = lat[i];
    int pos = atomicAdd(&cursor[g], 1);
    sorted[pos] = i;
  }
}

// ---------- mu/sig mini-GEMM, dtype-templated, self-disabling ----------
template <bool F32>
__global__ void k_musig(const void* __restrict__ of, const void* __restrict__ Wmu,
                        const void* __restrict__ bmu, const void* __restrict__ Wsig,
                        const void* __restrict__ bsig, const int* __restrict__ flag,
                        float* __restrict__ mug, float* __restrict__ sgg, int total) {
  if ((*flag != 0) != F32) return;
  int idx = blockIdx.x * blockDim.x + threadIdx.x;
  if (idx >= total) return;
  int g = idx >> 6, c = idx & 63;
  float a0 = 0.f, a1 = 0.f, bm, bs;
  if (F32) {
    const float* ofr = (const float*)of + (size_t)g * 128;
    const float* wm = (const float*)Wmu;
    const float* wsv = (const float*)Wsig;
    for (int k = 0; k < 128; k++) {
      float ov = ofr[k];
      a0 = fmaf(ov, wm[k * 64 + c], a0);
      a1 = fmaf(ov, wsv[k * 64 + c], a1);
    }
    bm = ((const float*)bmu)[c];
    bs = ((const float*)bsig)[c];
  } else {
    const u16* ofr = (const u16*)of + (size_t)g * 128;
    const u16* wm = (const u16*)Wmu;
    const u16* wsv = (const u16*)Wsig;
    for (int k = 0; k < 128; k++) {
      float ov = bf2f((u32)ofr[k]);
      a0 = fmaf(ov, bf2f((u32)wm[k * 64 + c]), a0);
      a1 = fmaf(ov, bf2f((u32)wsv[k * 64 + c]), a1);
    }
    bm = bf2f((u32)((const u16*)bmu)[c]);
    bs = bf2f((u32)((const u16*)bsig)[c]);
  }
  mug[idx] = a0 + bm;
  sgg[idx] = a1 + bs;
}

// ---------- per-point h, bf16 row (8 uint4 = 64 bf16) ----------
__device__ __forceinline__ float h_bf16(const uint4* __restrict__ xr,
                                        const float* wcol, float bc) {
  float h0 = bc, h1 = 0.f, h2 = 0.f, h3 = 0.f;
#pragma unroll
  for (int j = 0; j < 8; j++) {
    uint4 q = xr[j];
    u32 qs[4] = {q.x, q.y, q.z, q.w};
#pragma unroll
    for (int m = 0; m < 4; m++) {
      float flo = __uint_as_float(qs[m] << 16);
      float fhi = __uint_as_float(qs[m] & 0xffff0000u);
      int k = j * 8 + m * 2;
      if ((m & 1) == 0) { h0 = fmaf(flo, wcol[k], h0); h1 = fmaf(fhi, wcol[k + 1], h1); }
      else             { h2 = fmaf(flo, wcol[k], h2); h3 = fmaf(fhi, wcol[k + 1], h3); }
    }
  }
  return (h0 + h2) + (h1 + h3);
}

// ---------- per-point h, fp32 row (16 float4 = 64 f32) ----------
__device__ __forceinline__ float h_f32(const float4* __restrict__ xr,
                                       const float* wcol, float bc) {
  float h0 = bc, h1 = 0.f, h2 = 0.f, h3 = 0.f;
#pragma unroll
  for (int j = 0; j < 16; j++) {
    float4 q = xr[j];
    int k = j * 4;
    h0 = fmaf(q.x, wcol[k], h0);
    h1 = fmaf(q.y, wcol[k + 1], h1);
    h2 = fmaf(q.z, wcol[k + 2], h2);
    h3 = fmaf(q.w, wcol[k + 3], h3);
  }
  return (h0 + h2) + (h1 + h3);
}

// ---------- main: block=group, wave=point, lane=channel ----------
template <bool F32>
__global__ void k_main(const void* __restrict__ x, const int* __restrict__ sorted,
                       const int* __restrict__ offs, const float* __restrict__ mug,
                       const float* __restrict__ sgg, const void* __restrict__ Wfc,
                       const void* __restrict__ bfc, const int* __restrict__ flag,
                       void* __restrict__ out) {
  if ((*flag != 0) != F32) return;
  int g = blockIdx.x;
  int lane = threadIdx.x & 63;
  int wid = threadIdx.x >> 6;
  int beg = offs[g], end = offs[g + 1];
  int cnt = end - beg;
  if (cnt == 0) return;
  __shared__ float red[2][4][64];

  float wcol[64];
  float bc;
  if (F32) {
    const float* W = (const float*)Wfc;
#pragma unroll
    for (int k = 0; k < 64; k++) wcol[k] = W[k * 64 + lane];
    bc = ((const float*)bfc)[lane];
  } else {
    const u16* W = (const u16*)Wfc;
#pragma unroll
    for (int k = 0; k < 64; k++) wcol[k] = bf2f((u32)W[k * 64 + lane]);
    bc = bf2f((u32)((const u16*)bfc)[lane]);
  }

  float ssum = 0.f, ssq = 0.f;
  for (int i = beg + wid; i < end; i += 4) {
    int p = __builtin_amdgcn_readfirstlane(sorted[i]);
    float h;
    if (F32) h = h_f32(reinterpret_cast<const float4*>(x) + (size_t)p * 16, wcol, bc);
    else     h = h_bf16(reinterpret_cast<const uint4*>(x) + (size_t)p * 8, wcol, bc);
    ssum += h;
    ssq = fmaf(h, h, ssq);
  }
  red[0][wid][lane] = ssum;
  red[1][wid][lane] = ssq;
  __syncthreads();
  float ts = 0.f, tq = 0.f;
#pragma unroll
  for (int w = 0; w < 4; w++) { ts += red[0][w][lane]; tq += red[1][w][lane]; }
  float inv = 1.0f / (float)cnt;
  float mean = ts * inv;
  float var = fmaxf(tq * inv - mean * mean, 0.f);
  float rstd = rsqrtf(var + 1e-14f);
  float scale = sgg[(size_t)g * 64 + lane] * rstd;
  float shift = mug[(size_t)g * 64 + lane] - mean * scale;

  for (int i = beg + wid; i < end; i += 4) {
    int p = __builtin_amdgcn_readfirstlane(sorted[i]);
    float h;
    if (F32) h = h_f32(reinterpret_cast<const float4*>(x) + (size_t)p * 16, wcol, bc);
    else     h = h_bf16(reinterpret_cast<const uint4*>(x) + (size_t)p * 8, wcol, bc);
    float o = fmaxf(fmaf(h, scale, shift), 0.f);
    if (F32) ((float*)out)[(size_t)p * 64 + lane] = o;
    else ((__hip_bfloat16*)out)[(size_t)p * 64 + lane] = __float2bfloat16(o);
  }
}

extern "C" void kernel_launch(void* const* d_in, const int* in_sizes, int n_in,
                              void* d_out, int out_size, void* d_ws, size_t ws_size,
                              hipStream_t stream) {
  const void* x   = d_in[0];
  const void* of  = d_in[1];
  const int* lat  = (const int*)d_in[2];
  const void* Wfc = d_in[4];
  const void* bfc = d_in[5];
  const void* Wmu = d_in[6];
  const void* bmu = d_in[7];
  const void* Wsg = d_in[8];
  const void* bsg = d_in[9];

  int N = in_sizes[2];
  int G = in_sizes[1] / 128;

  char* ws = (char*)d_ws;
  size_t o = 0;
  int* flag   = (int*)(ws + o); o += 256;  // aligned block for flag
  int* cnt    = (int*)(ws + o); o += (size_t)G * 4;
  int* offs   = (int*)(ws + o); o += (size_t)(G + 1) * 4;
  int* cursor = (int*)(ws + o); o += (size_t)G * 4;
  o = (o + 255) & ~(size_t)255;
  float* mug  = (float*)(ws + o); o += (size_t)G * 64 * 4;
  float* sgg  = (float*)(ws + o); o += (size_t)G * 64 * 4;
  int* sorted = (int*)(ws + o); o += (size_t)N * 4;  // total ~6.3 MB

  FCAdaINLayer_68719477052_kernel<<<64, 256, 0, stream>>>((const u16*)x, cnt, G, flag);
  k_hist<<<1024, 256, 0, stream>>>(lat, N, cnt);
  k_scan<<<1, 256, 0, stream>>>(cnt, G, offs, cursor);
  k_scatter<<<1024, 256, 0, stream>>>(lat, N, cursor, sorted);
  k_musig<false><<<(G * 64 + 255) / 256, 256, 0, stream>>>(of, Wmu, bmu, Wsg, bsg, flag, mug, sgg, G * 64);
  k_musig<true><<<(G * 64 + 255) / 256, 256, 0, stream>>>(of, Wmu, bmu, Wsg, bsg, flag, mug, sgg, G * 64);
  k_main<false><<<G, 256, 0, stream>>>(x, sorted, offs, mug, sgg, Wfc, bfc, flag, d_out);
  k_main<true><<<G, 256, 0, stream>>>(x, sorted, offs, mug, sgg, Wfc, bfc, flag, d_out);
}

// Round 3
// 957.628 us; speedup vs baseline: 1.0457x; 1.0457x over previous
//
#include <hip/hip_runtime.h>
#include <hip/hip_bf16.h>
#include <stdint.h>

typedef unsigned int u32;

// ---------- init: zero group counters (keeps harness kernel symbol) ----------
__global__ void FCAdaINLayer_68719477052_kernel(int* __restrict__ cnt, int G) {
  int t = blockIdx.x * blockDim.x + threadIdx.x;
  int stride = gridDim.x * blockDim.x;
  for (int i = t; i < G; i += stride) cnt[i] = 0;
}

// ---------- histogram ----------
__global__ void k_hist(const int* __restrict__ lat, int n, int* __restrict__ cnt) {
  int i = blockIdx.x * blockDim.x + threadIdx.x;
  int stride = gridDim.x * blockDim.x;
  for (; i < n; i += stride) atomicAdd(&cnt[lat[i]], 1);
}

// ---------- exclusive scan (1 block, 256 thr) ----------
__global__ void k_scan(const int* __restrict__ cnt, int G, int* __restrict__ offs,
                       int* __restrict__ cursor) {
  __shared__ int part[256];
  int t = threadIdx.x;
  int per = (G + 255) / 256;
  int base = t * per;
  int s = 0;
  for (int j = 0; j < per; j++) { int g = base + j; if (g < G) s += cnt[g]; }
  part[t] = s;
  __syncthreads();
  if (t == 0) {
    int run = 0;
    for (int j = 0; j < 256; j++) { int v = part[j]; part[j] = run; run += v; }
  }
  __syncthreads();
  int run = part[t];
  for (int j = 0; j < per; j++) {
    int g = base + j;
    if (g < G) { offs[g] = run; cursor[g] = run; run += cnt[g]; }
  }
  if (t == 255) offs[G] = run;
}

// ---------- scatter ----------
__global__ void k_scatter(const int* __restrict__ lat, int n, int* __restrict__ cursor,
                          int* __restrict__ sorted) {
  int i = blockIdx.x * blockDim.x + threadIdx.x;
  int stride = gridDim.x * blockDim.x;
  for (; i < n; i += stride) {
    int g = lat[i];
    int pos = atomicAdd(&cursor[g], 1);
    sorted[pos] = i;
  }
}

// ---------- mu/sig mini-GEMM (fp32) ----------
__global__ void k_musig(const float* __restrict__ of, const float* __restrict__ Wmu,
                        const float* __restrict__ bmu, const float* __restrict__ Wsig,
                        const float* __restrict__ bsig, float* __restrict__ mug,
                        float* __restrict__ sgg, int total) {
  int idx = blockIdx.x * blockDim.x + threadIdx.x;
  if (idx >= total) return;
  int g = idx >> 6, c = idx & 63;
  const float* ofr = of + (size_t)g * 128;
  float a0 = 0.f, a1 = 0.f;
  for (int k = 0; k < 128; k++) {
    float ov = ofr[k];
    a0 = fmaf(ov, Wmu[k * 64 + c], a0);
    a1 = fmaf(ov, Wsig[k * 64 + c], a1);
  }
  mug[idx] = a0 + bmu[c];
  sgg[idx] = a1 + bsig[c];
}

// dot of a 64-float row (16 float4 reads, uniform address) with per-lane wcol
__device__ __forceinline__ float dot64(const float4* __restrict__ xr,
                                       const float* wcol, float bc) {
  float h0 = bc, h1 = 0.f, h2 = 0.f, h3 = 0.f;
#pragma unroll
  for (int j = 0; j < 16; j++) {
    float4 q = xr[j];
    int k = j * 4;
    h0 = fmaf(q.x, wcol[k], h0);
    h1 = fmaf(q.y, wcol[k + 1], h1);
    h2 = fmaf(q.z, wcol[k + 2], h2);
    h3 = fmaf(q.w, wcol[k + 3], h3);
  }
  return (h0 + h2) + (h1 + h3);
}

// ---------- main: block=group; stage rows in LDS; h overwrites its LDS row ----------
#define ROWS 312  // 312*256B = 79872B + 2KB red = 80KB -> 2 blocks/CU
__global__ __launch_bounds__(256) void k_main(
    const float* __restrict__ x, const int* __restrict__ sorted,
    const int* __restrict__ offs, const float* __restrict__ mug,
    const float* __restrict__ sgg, const float* __restrict__ Wfc,
    const float* __restrict__ bfc, float* __restrict__ out) {
  __shared__ float xs[ROWS * 64];
  __shared__ float red[2][4][64];
  int g = blockIdx.x;
  int beg = offs[g], end = offs[g + 1];
  int cnt = end - beg;
  if (cnt == 0) return;
  int tid = threadIdx.x;
  int lane = tid & 63, wid = tid >> 6;
  int rows = cnt < ROWS ? cnt : ROWS;

  // stage: coalesced float4 loads; 16 threads cover one 256B row
  for (int idx = tid; idx < rows * 16; idx += 256) {
    int j = idx >> 4, e = idx & 15;
    int p = sorted[beg + j];
    reinterpret_cast<float4*>(xs)[j * 16 + e] =
        reinterpret_cast<const float4*>(x + (size_t)p * 64)[e];
  }
  __syncthreads();

  // per-lane column of W_fc
  float wcol[64];
#pragma unroll
  for (int k = 0; k < 64; k++) wcol[k] = Wfc[k * 64 + lane];
  float bc = bfc[lane];

  // phase 1: h per point; write h back over the row (row owned by this wave)
  float ssum = 0.f, ssq = 0.f;
  for (int j = wid; j < cnt; j += 8) {  // 2-pt unroll for ILP
    int j2 = j + 4;
    float h1;
    if (j < ROWS) {
      h1 = dot64(reinterpret_cast<const float4*>(xs + j * 64), wcol, bc);
      xs[j * 64 + lane] = h1;
    } else {
      int p = __builtin_amdgcn_readfirstlane(sorted[beg + j]);
      h1 = dot64(reinterpret_cast<const float4*>(x + (size_t)p * 64), wcol, bc);
    }
    ssum += h1;
    ssq = fmaf(h1, h1, ssq);
    if (j2 < cnt) {
      float h2;
      if (j2 < ROWS) {
        h2 = dot64(reinterpret_cast<const float4*>(xs + j2 * 64), wcol, bc);
        xs[j2 * 64 + lane] = h2;
      } else {
        int p = __builtin_amdgcn_readfirstlane(sorted[beg + j2]);
        h2 = dot64(reinterpret_cast<const float4*>(x + (size_t)p * 64), wcol, bc);
      }
      ssum += h2;
      ssq = fmaf(h2, h2, ssq);
    }
  }
  red[0][wid][lane] = ssum;
  red[1][wid][lane] = ssq;
  __syncthreads();
  float ts = 0.f, tq = 0.f;
#pragma unroll
  for (int w = 0; w < 4; w++) { ts += red[0][w][lane]; tq += red[1][w][lane]; }
  float inv = 1.0f / (float)cnt;
  float mean = ts * inv;
  float var = fmaxf(tq * inv - mean * mean, 0.f);
  float rstd = rsqrtf(var + 1e-14f);
  float scale = sgg[(size_t)g * 64 + lane] * rstd;
  float shift = mug[(size_t)g * 64 + lane] - mean * scale;

  // phase 2: h from LDS (same wave wrote it), affine+relu, coalesced store
  for (int j = wid; j < cnt; j += 4) {
    int p = __builtin_amdgcn_readfirstlane(sorted[beg + j]);
    float h;
    if (j < ROWS) {
      h = xs[j * 64 + lane];
    } else {
      h = dot64(reinterpret_cast<const float4*>(x + (size_t)p * 64), wcol, bc);
    }
    out[(size_t)p * 64 + lane] = fmaxf(fmaf(h, scale, shift), 0.f);
  }
}

extern "C" void kernel_launch(void* const* d_in, const int* in_sizes, int n_in,
                              void* d_out, int out_size, void* d_ws, size_t ws_size,
                              hipStream_t stream) {
  const float* x   = (const float*)d_in[0];   // [N,64] fp32
  const float* of  = (const float*)d_in[1];   // [G,128] fp32
  const int* lat   = (const int*)d_in[2];     // [N] int32
  const float* Wfc = (const float*)d_in[4];   // [64,64]
  const float* bfc = (const float*)d_in[5];   // [64]
  const float* Wmu = (const float*)d_in[6];   // [128,64]
  const float* bmu = (const float*)d_in[7];   // [64]
  const float* Wsg = (const float*)d_in[8];   // [128,64]
  const float* bsg = (const float*)d_in[9];   // [64]

  int N = in_sizes[2];
  int G = in_sizes[1] / 128;

  char* ws = (char*)d_ws;
  size_t o = 0;
  int* cnt    = (int*)(ws + o); o += (size_t)G * 4;
  int* offs   = (int*)(ws + o); o += (size_t)(G + 1) * 4;
  int* cursor = (int*)(ws + o); o += (size_t)G * 4;
  o = (o + 255) & ~(size_t)255;
  float* mug  = (float*)(ws + o); o += (size_t)G * 64 * 4;
  float* sgg  = (float*)(ws + o); o += (size_t)G * 64 * 4;
  int* sorted = (int*)(ws + o); o += (size_t)N * 4;  // ~6.3 MB total

  FCAdaINLayer_68719477052_kernel<<<32, 256, 0, stream>>>(cnt, G);
  k_hist<<<1024, 256, 0, stream>>>(lat, N, cnt);
  k_scan<<<1, 256, 0, stream>>>(cnt, G, offs, cursor);
  k_scatter<<<1024, 256, 0, stream>>>(lat, N, cursor, sorted);
  k_musig<<<(G * 64 + 255) / 256, 256, 0, stream>>>(of, Wmu, bmu, Wsg, bsg, mug, sgg, G * 64);
  k_main<<<G, 256, 0, stream>>>(x, sorted, offs, mug, sgg, Wfc, bfc, (float*)d_out);
}